// Round 21
// baseline (1585.075 us; speedup 1.0000x reference)
//
#include <hip/hip_runtime.h>
#include <hip/hip_bf16.h>

#define D_DIM 512
#define S_LEN 12
#define H_NUM 8
#define WMAT 262144       // 512*512

// ---- kernel1: G_B=8, 96 rows, 12 waves, M-split QKV + manual 3-stream B dbuf ----
#define G_B1 8
#define ROWS1 96          // 6 M-tiles
#define THREADS1 768      // 12 waves
#define X_OFF   0         // [96][512] bf16 = 98304
#define Q_OFF   98304     // [96][64] bf16 = 12288
#define K_OFF   110592
#define V_OFF   122880
#define P_OFF   135168    // 8 x [12][20] f32 = 7680
#define SMEM1   142848    // 1 block/CU

// ---- kernel2 (R15-proven): G_B=8, 512 threads, Y[6][4] ----
#define G_B2 8
#define ROWS2 96
#define THREADS2 512
#define AST_OFF 0         // [96][512] bf16 = 98304
#define RED_OFF 98304     // [96][17] f32 = 6528
#define MU_OFF  104832    // [96][2] f32 = 768
#define SMEM2   105600    // 1 block/CU

// A intermediate: bf16, row r at u16-elem index r*1024 + c (low 1024 B of row r's
// 2048 B f32 slot in d_out). K2 block reads exactly the bytes it later overwrites.

typedef __attribute__((ext_vector_type(8))) short bf16x8;
typedef __attribute__((ext_vector_type(4))) float f32x4;

__device__ __forceinline__ unsigned short f2bf(float f) {
    union { float f; unsigned u; } c; c.f = f;
    unsigned r = c.u + 0x7fffu + ((c.u >> 16) & 1u);
    return (unsigned short)(r >> 16);
}
__device__ __forceinline__ float bf2f(unsigned short u) {
    union { unsigned u; float f; } c; c.u = ((unsigned)u) << 16;
    return c.f;
}
// 16B-granule XOR swizzle, 512-col tiles
__device__ __forceinline__ int xswc(int row, int col) {
    return row * 512 + (((col >> 3) ^ (row & 7)) << 3) + (col & 7);
}
// 64-col tiles, stride 64, 16B-chunk XOR
__device__ __forceinline__ int qsw(int row, int col) {
    return row * 64 + (((col >> 3) ^ (row & 7)) << 3) + (col & 7);
}

__global__ void prep_weights(const float* __restrict__ Wq, const float* __restrict__ Wk,
                             const float* __restrict__ Wv, const float* __restrict__ Wo,
                             unsigned short* __restrict__ wt) {
    int idx = blockIdx.x * 256 + threadIdx.x;   // 0 .. 4*WMAT-1
    int mat = idx >> 18;
    int rem = idx & (WMAT - 1);
    int e = rem >> 9, d = rem & 511;
    const float* W = (mat == 0) ? Wq : (mat == 1) ? Wk : (mat == 2) ? Wv : Wo;
    wt[idx] = f2bf(W[d * D_DIM + e]);           // wt[mat][e][d] = W[d][e]
}

// ---------------- kernel 1: QKV (M-split, B-dbuf) + attention -> A (bf16, packed) ----------------
__global__ __launch_bounds__(THREADS1, 3) void qkv_attn(
    const float* __restrict__ x, const unsigned short* __restrict__ wt,
    const float* __restrict__ bq, const float* __restrict__ bk, const float* __restrict__ bv,
    const float* __restrict__ adj, unsigned short* __restrict__ aout)
{
    extern __shared__ char smem[];
    unsigned short* Xh = (unsigned short*)(smem + X_OFF);
    unsigned short* Qh = (unsigned short*)(smem + Q_OFF);
    unsigned short* Kh = (unsigned short*)(smem + K_OFF);
    unsigned short* Vh = (unsigned short*)(smem + V_OFF);
    float* Pl = (float*)(smem + P_OFF);         // [8][12][20]

    const int tid  = threadIdx.x;
    const int lane = tid & 63;
    const int w    = tid >> 6;          // wave 0..11
    const int lr   = lane & 15;
    const int lg   = lane >> 4;
    const int lr12 = (lr < 12) ? lr : 11;       // true clamp
    const size_t row0 = (size_t)blockIdx.x * ROWS1;

    // stage X -> LDS bf16 (swizzled): 12288 float4 chunks, 16/thread (ONCE)
    #pragma unroll
    for (int it = 0; it < 16; ++it) {
        int idx = it * THREADS1 + tid;
        int r = idx >> 7, col = (idx & 127) << 2;
        float4 v = *(const float4*)(x + (row0 + r) * (size_t)D_DIM + col);
        ushort4 pk;
        pk.x = f2bf(v.x); pk.y = f2bf(v.y); pk.z = f2bf(v.z); pk.w = f2bf(v.w);
        *(ushort4*)(Xh + xswc(r, col)) = pk;
    }
    __syncthreads();

    // QKV task split: wave (mg, cgrp) = M-group mg (rows mg*32..+31, 2 M-tiles)
    //                 x col-group cgrp (3 of the 12 (mat,colt) tiles of the head).
    const int mg   = w >> 2;            // 0..2
    const int cgrp = w & 3;             // 0..3
    int mati[3], colti[3];
    #pragma unroll
    for (int i = 0; i < 3; ++i) {
        int tt = cgrp * 3 + i;
        mati[i]  = tt >> 2;
        colti[i] = tt & 3;
    }
    const int rb = w * S_LEN;           // attention rows (waves 0-7)

    #pragma unroll 1
    for (int h = 0; h < H_NUM; ++h) {
        // ---------------- QKV projection: 2 af-reads -> 6 MFMA, B dbuf'd ----------------
        f32x4 acc[2][3];
        #pragma unroll
        for (int mt = 0; mt < 2; ++mt)
            #pragma unroll
            for (int i = 0; i < 3; ++i) acc[mt][i] = (f32x4){0.f, 0.f, 0.f, 0.f};

        const unsigned short* bp0 = wt + (size_t)mati[0] * WMAT + (h * 64 + colti[0] * 16 + lr) * D_DIM + lg * 8;
        const unsigned short* bp1 = wt + (size_t)mati[1] * WMAT + (h * 64 + colti[1] * 16 + lr) * D_DIM + lg * 8;
        const unsigned short* bp2 = wt + (size_t)mati[2] * WMAT + (h * 64 + colti[2] * 16 + lr) * D_DIM + lg * 8;

        // manual double-buffer (R8-proven pattern, 3 streams, named scalars)
        bf16x8 bc0 = *(const bf16x8*)(bp0);
        bf16x8 bc1 = *(const bf16x8*)(bp1);
        bf16x8 bc2 = *(const bf16x8*)(bp2);
        #pragma unroll
        for (int ks = 0; ks < 16; ++ks) {
            bf16x8 bn0, bn1, bn2;
            if (ks < 15) {
                bn0 = *(const bf16x8*)(bp0 + (ks + 1) * 32);
                bn1 = *(const bf16x8*)(bp1 + (ks + 1) * 32);
                bn2 = *(const bf16x8*)(bp2 + (ks + 1) * 32);
            }
            bf16x8 af0 = *(const bf16x8*)(Xh + xswc(mg * 32 + lr,      ks * 32 + lg * 8));
            bf16x8 af1 = *(const bf16x8*)(Xh + xswc(mg * 32 + 16 + lr, ks * 32 + lg * 8));
            acc[0][0] = __builtin_amdgcn_mfma_f32_16x16x32_bf16(af0, bc0, acc[0][0], 0, 0, 0);
            acc[1][0] = __builtin_amdgcn_mfma_f32_16x16x32_bf16(af1, bc0, acc[1][0], 0, 0, 0);
            acc[0][1] = __builtin_amdgcn_mfma_f32_16x16x32_bf16(af0, bc1, acc[0][1], 0, 0, 0);
            acc[1][1] = __builtin_amdgcn_mfma_f32_16x16x32_bf16(af1, bc1, acc[1][1], 0, 0, 0);
            acc[0][2] = __builtin_amdgcn_mfma_f32_16x16x32_bf16(af0, bc2, acc[0][2], 0, 0, 0);
            acc[1][2] = __builtin_amdgcn_mfma_f32_16x16x32_bf16(af1, bc2, acc[1][2], 0, 0, 0);
            if (ks < 15) { bc0 = bn0; bc1 = bn1; bc2 = bn2; }
        }
        // store this wave's tiles (+bias): rows mg*32..+31, tile cols
        #pragma unroll
        for (int i = 0; i < 3; ++i) {
            unsigned short* T = (mati[i] == 0) ? Qh : (mati[i] == 1) ? Kh : Vh;
            const float* bsel = (mati[i] == 0) ? bq : (mati[i] == 1) ? bk : bv;
            int colh = colti[i] * 16 + lr;
            float bias = bsel[h * 64 + colh];
            #pragma unroll
            for (int mt = 0; mt < 2; ++mt)
                #pragma unroll
                for (int j = 0; j < 4; ++j)
                    T[qsw(mg * 32 + mt * 16 + lg * 4 + j, colh)] = f2bf(acc[mt][i][j] + bias);
        }
        __syncthreads();   // Q/K/V complete

        // ---------------- attention (waves 0-7 <-> batch items 0-7) ----------------
        if (w < 8) {
            f32x4 sacc = (f32x4){0.f, 0.f, 0.f, 0.f};
            #pragma unroll
            for (int k2 = 0; k2 < 2; ++k2) {
                bf16x8 ak = *(const bf16x8*)(Kh + qsw(rb + lr12, k2 * 32 + lg * 8));
                bf16x8 aq = *(const bf16x8*)(Qh + qsw(rb + lr12, k2 * 32 + lg * 8));
                sacc = __builtin_amdgcn_mfma_f32_16x16x32_bf16(ak, aq, sacc, 0, 0, 0);
            }
            float ab4[4] = {0.f, 0.f, 0.f, 0.f};
            if (lg < 3 && lr < 12) {
                float4 t4 = *(const float4*)(adj + (h * S_LEN + lr) * S_LEN + lg * 4);
                ab4[0] = t4.x; ab4[1] = t4.y; ab4[2] = t4.z; ab4[3] = t4.w;
            }
            float sc[4], e4[4];
            float m = -1e30f;
            #pragma unroll
            for (int j = 0; j < 4; ++j) {
                int t = lg * 4 + j;
                sc[j] = (t < 12) ? (sacc[j] * 0.125f + ab4[j]) : -1e30f;
                m = fmaxf(m, sc[j]);
            }
            m = fmaxf(m, __shfl_xor(m, 16));
            m = fmaxf(m, __shfl_xor(m, 32));
            float ssum = 0.f;
            #pragma unroll
            for (int j = 0; j < 4; ++j) { e4[j] = __expf(sc[j] - m); ssum += e4[j]; }
            ssum += __shfl_xor(ssum, 16);
            ssum += __shfl_xor(ssum, 32);
            float inv = 1.f / ssum;
            float* Pw = Pl + w * 240;
            if (lr < 12 && lg < 3) {
                f32x4 pvec = (f32x4){e4[0] * inv, e4[1] * inv, e4[2] * inv, e4[3] * inv};
                *(f32x4*)(Pw + lr * 20 + lg * 4) = pvec;
            }
            // same-wave P write -> read: no barrier needed (validated R5-R20)
            float vv[12];
            #pragma unroll
            for (int t = 0; t < 12; ++t) vv[t] = bf2f(Vh[qsw(rb + t, lane)]);
            #pragma unroll
            for (int ss = 0; ss < 12; ++ss) {
                f32x4 pa = *(const f32x4*)(Pw + ss * 20);
                f32x4 pb = *(const f32x4*)(Pw + ss * 20 + 4);
                f32x4 pc = *(const f32x4*)(Pw + ss * 20 + 8);
                float o = 0.f;
                #pragma unroll
                for (int t = 0; t < 4; ++t) o += pa[t] * vv[t];
                #pragma unroll
                for (int t = 0; t < 4; ++t) o += pb[t] * vv[4 + t];
                #pragma unroll
                for (int t = 0; t < 4; ++t) o += pc[t] * vv[8 + t];
                // bf16 A, packed: row r's data at u16-elem r*1024 + col
                aout[(row0 + rb + ss) * 1024 + h * 64 + lane] = f2bf(o);
            }
        }
        __syncthreads();   // A consumers done; safe to overwrite Q/K/V next head
    }
}

// ---------------- kernel 2: out-proj + bias + residual + LayerNorm (in-place) ----------------
__global__ __launch_bounds__(THREADS2, 2) void oproj_ln(
    const float* __restrict__ x, const unsigned short* __restrict__ wt,
    const float* __restrict__ bo, const float* __restrict__ gamma,
    const float* __restrict__ beta, float* __restrict__ out)
{
    extern __shared__ char smem[];
    unsigned short* Ast = (unsigned short*)(smem + AST_OFF);  // [96][512] bf16
    float* red   = (float*)(smem + RED_OFF);   // [96][17]
    float* musig = (float*)(smem + MU_OFF);    // [96][2]

    const int tid  = threadIdx.x;
    const int lane = tid & 63;
    const int w    = tid >> 6;          // wave 0..7, cols [w*64, w*64+64)
    const int lr   = lane & 15;
    const int lg   = lane >> 4;
    const size_t row0 = (size_t)blockIdx.x * ROWS2;
    const unsigned short* abase = (const unsigned short*)out;  // bf16 A region

    // stage A (bf16, low half of each row's f32 slot) -> LDS, straight 16B copy.
    #pragma unroll
    for (int it = 0; it < 12; ++it) {
        int idx = it * THREADS2 + tid;
        int r = idx >> 6, c8 = (idx & 63) << 3;
        uint4 v = *(const uint4*)(abase + (row0 + r) * 1024 + c8);
        *(uint4*)(Ast + xswc(r, c8)) = v;
    }
    __syncthreads();

    f32x4 Y[6][4];
    #pragma unroll
    for (int mt = 0; mt < 6; ++mt)
        #pragma unroll
        for (int nt = 0; nt < 4; ++nt) Y[mt][nt] = (f32x4){0.f, 0.f, 0.f, 0.f};

    const unsigned short* obase = wt + (size_t)3 * WMAT + (w * 64 + lr) * D_DIM;
    #pragma unroll 1
    for (int ks = 0; ks < 16; ++ks) {
        bf16x8 afr[6];
        #pragma unroll
        for (int mt = 0; mt < 6; ++mt)
            afr[mt] = *(const bf16x8*)(Ast + xswc(mt * 16 + lr, ks * 32 + lg * 8));
        #pragma unroll
        for (int nt = 0; nt < 4; ++nt) {
            bf16x8 bfr = *(const bf16x8*)(obase + nt * 16 * D_DIM + ks * 32 + lg * 8);
            #pragma unroll
            for (int mt = 0; mt < 6; ++mt)
                Y[mt][nt] = __builtin_amdgcn_mfma_f32_16x16x32_bf16(afr[mt], bfr, Y[mt][nt], 0, 0, 0);
        }
    }

    // epilogue: +bo, +x (fp32), LayerNorm, store
    float bo4[4], gm4[4], bt4[4];
    int cols[4];
    #pragma unroll
    for (int nt = 0; nt < 4; ++nt) {
        cols[nt] = w * 64 + nt * 16 + lr;
        bo4[nt] = bo[cols[nt]]; gm4[nt] = gamma[cols[nt]]; bt4[nt] = beta[cols[nt]];
    }
    #pragma unroll
    for (int mt = 0; mt < 6; ++mt)
        #pragma unroll
        for (int j = 0; j < 4; ++j) {
            int rowl = mt * 16 + lg * 4 + j;
            const float* xrow = x + (row0 + rowl) * (size_t)D_DIM;
            float ps = 0.f, pq = 0.f;
            #pragma unroll
            for (int nt = 0; nt < 4; ++nt) {
                float y = Y[mt][nt][j] + bo4[nt] + xrow[cols[nt]];
                Y[mt][nt][j] = y;
                ps += y; pq += y * y;
            }
            ps += __shfl_xor(ps, 1); pq += __shfl_xor(pq, 1);
            ps += __shfl_xor(ps, 2); pq += __shfl_xor(pq, 2);
            ps += __shfl_xor(ps, 4); pq += __shfl_xor(pq, 4);
            ps += __shfl_xor(ps, 8); pq += __shfl_xor(pq, 8);
            if (lr == 0) { red[rowl * 17 + w * 2] = ps; red[rowl * 17 + w * 2 + 1] = pq; }
        }
    __syncthreads();
    if (tid < ROWS2) {
        float s = 0.f, q = 0.f;
        #pragma unroll
        for (int w8 = 0; w8 < 8; ++w8) { s += red[tid * 17 + w8 * 2]; q += red[tid * 17 + w8 * 2 + 1]; }
        float mu = s * (1.f / 512.f);
        float var = q * (1.f / 512.f) - mu * mu;
        musig[tid * 2] = mu;
        musig[tid * 2 + 1] = rsqrtf(var + 1e-5f);
    }
    __syncthreads();
    #pragma unroll
    for (int mt = 0; mt < 6; ++mt)
        #pragma unroll
        for (int j = 0; j < 4; ++j) {
            int rowl = mt * 16 + lg * 4 + j;
            float mu = musig[rowl * 2], rs = musig[rowl * 2 + 1];
            float* orow = out + (row0 + rowl) * (size_t)D_DIM;
            #pragma unroll
            for (int nt = 0; nt < 4; ++nt)
                orow[cols[nt]] = (Y[mt][nt][j] - mu) * rs * gm4[nt] + bt4[nt];
        }
}

extern "C" void kernel_launch(void* const* d_in, const int* in_sizes, int n_in,
                              void* d_out, int out_size, void* d_ws, size_t ws_size,
                              hipStream_t stream) {
    (void)in_sizes; (void)n_in; (void)out_size; (void)ws_size;
    const float* x     = (const float*)d_in[0];
    const float* Wq    = (const float*)d_in[1];
    const float* bq    = (const float*)d_in[2];
    const float* Wk    = (const float*)d_in[3];
    const float* bk    = (const float*)d_in[4];
    const float* Wv    = (const float*)d_in[5];
    const float* bv    = (const float*)d_in[6];
    const float* adj   = (const float*)d_in[7];
    const float* Wo    = (const float*)d_in[8];
    const float* bo    = (const float*)d_in[9];
    const float* gamma = (const float*)d_in[10];
    const float* beta  = (const float*)d_in[11];
    unsigned short* wt = (unsigned short*)d_ws;      // 4 * 512*512 bf16 = 2 MiB

    prep_weights<<<4096, 256, 0, stream>>>(Wq, Wk, Wv, Wo, wt);
    qkv_attn<<<16384 / G_B1, THREADS1, SMEM1, stream>>>(
        x, wt, bq, bk, bv, adj, (unsigned short*)d_out);
    oproj_ln<<<16384 / G_B2, THREADS2, SMEM2, stream>>>(
        x, wt, bo, gamma, beta, (float*)d_out);
}

// Round 22
// 943.417 us; speedup vs baseline: 1.6801x; 1.6801x over previous
//
#include <hip/hip_runtime.h>
#include <hip/hip_bf16.h>

#define D_DIM 512
#define S_LEN 12
#define H_NUM 8
#define WMAT 262144       // 512*512

// ---- kernel1 (R8/R15-proven): G_B=8, 96 rows, 12 waves ----
#define G_B1 8
#define ROWS1 96          // 6 M-tiles
#define THREADS1 768      // 12 waves: wave = (mat, colt)
#define X_OFF   0         // [96][512] bf16 = 98304
#define Q_OFF   98304     // [96][64] bf16 = 12288
#define K_OFF   110592
#define V_OFF   122880
#define P_OFF   135168    // 8 x [12][20] f32 = 7680
#define SMEM1   142848    // 1 block/CU

// ---- kernel2 (R15-proven): G_B=8, 512 threads, Y[6][4] ----
#define G_B2 8
#define ROWS2 96
#define THREADS2 512
#define AST_OFF 0         // [96][512] bf16 = 98304
#define RED_OFF 98304     // [96][17] f32 = 6528
#define MU_OFF  104832    // [96][2] f32 = 768
#define SMEM2   105600    // 1 block/CU

// A intermediate: bf16, row r at u16-elem index r*1024 + c (low 1024 B of row r's
// 2048 B f32 slot in d_out). K2 block reads exactly the bytes it later overwrites.

typedef __attribute__((ext_vector_type(8))) short bf16x8;
typedef __attribute__((ext_vector_type(4))) float f32x4;

__device__ __forceinline__ unsigned short f2bf(float f) {
    union { float f; unsigned u; } c; c.f = f;
    unsigned r = c.u + 0x7fffu + ((c.u >> 16) & 1u);
    return (unsigned short)(r >> 16);
}
__device__ __forceinline__ float bf2f(unsigned short u) {
    union { unsigned u; float f; } c; c.u = ((unsigned)u) << 16;
    return c.f;
}
// 16B-granule XOR swizzle, 512-col tiles
__device__ __forceinline__ int xswc(int row, int col) {
    return row * 512 + (((col >> 3) ^ (row & 7)) << 3) + (col & 7);
}
// 64-col tiles, stride 64, 16B-chunk XOR
__device__ __forceinline__ int qsw(int row, int col) {
    return row * 64 + (((col >> 3) ^ (row & 7)) << 3) + (col & 7);
}

__global__ void prep_weights(const float* __restrict__ Wq, const float* __restrict__ Wk,
                             const float* __restrict__ Wv, const float* __restrict__ Wo,
                             unsigned short* __restrict__ wt) {
    int idx = blockIdx.x * 256 + threadIdx.x;   // 0 .. 4*WMAT-1
    int mat = idx >> 18;
    int rem = idx & (WMAT - 1);
    int e = rem >> 9, d = rem & 511;
    const float* W = (mat == 0) ? Wq : (mat == 1) ? Wk : (mat == 2) ? Wv : Wo;
    wt[idx] = f2bf(W[d * D_DIM + e]);           // wt[mat][e][d] = W[d][e]
}

// ---------------- kernel 1: QKV + attention -> A (bf16, packed into d_out) ----------------
__global__ __launch_bounds__(THREADS1, 3) void qkv_attn(
    const float* __restrict__ x, const unsigned short* __restrict__ wt,
    const float* __restrict__ bq, const float* __restrict__ bk, const float* __restrict__ bv,
    const float* __restrict__ adj, unsigned short* __restrict__ aout)
{
    extern __shared__ char smem[];
    unsigned short* Xh = (unsigned short*)(smem + X_OFF);
    unsigned short* Qh = (unsigned short*)(smem + Q_OFF);
    unsigned short* Kh = (unsigned short*)(smem + K_OFF);
    unsigned short* Vh = (unsigned short*)(smem + V_OFF);
    float* Pl = (float*)(smem + P_OFF);         // [8][12][20]

    const int tid  = threadIdx.x;
    const int lane = tid & 63;
    const int w    = tid >> 6;          // wave 0..11
    const int lr   = lane & 15;
    const int lg   = lane >> 4;
    const int lr12 = (lr < 12) ? lr : 11;       // true clamp
    const size_t row0 = (size_t)blockIdx.x * ROWS1;

    // stage X -> LDS bf16 (swizzled): 12288 float4 chunks, 16 per thread
    #pragma unroll
    for (int it = 0; it < 16; ++it) {
        int idx = it * THREADS1 + tid;
        int r = idx >> 7, col = (idx & 127) << 2;
        float4 v = *(const float4*)(x + (row0 + r) * (size_t)D_DIM + col);
        ushort4 pk;
        pk.x = f2bf(v.x); pk.y = f2bf(v.y); pk.z = f2bf(v.z); pk.w = f2bf(v.w);
        *(ushort4*)(Xh + xswc(r, col)) = pk;
    }
    __syncthreads();

    // wave task: mat = w>>2 (0=Q,1=K,2=V), colt = w&3; owns all 6 M-tiles.
    const int mat  = w >> 2;
    const int colt = w & 3;
    const int colh = colt * 16 + lr;
    const float* bsel = (mat == 0) ? bq : (mat == 1) ? bk : bv;
    unsigned short* T = (mat == 0) ? Qh : (mat == 1) ? Kh : Vh;
    const int rb = w * S_LEN;                   // attention rows (waves 0-7)

    #pragma unroll 1
    for (int h = 0; h < H_NUM; ++h) {
        // ---------------- QKV projection for head h ----------------
        f32x4 acc[6];
        #pragma unroll
        for (int mt = 0; mt < 6; ++mt) acc[mt] = (f32x4){0.f, 0.f, 0.f, 0.f};

        const unsigned short* bAp = wt + (size_t)mat * WMAT + (h * 64 + colh) * D_DIM + lg * 8;
        bf16x8 bc = *(const bf16x8*)(bAp);      // B double-buffer: preload ks=0
        #pragma unroll
        for (int ks = 0; ks < 16; ++ks) {
            bf16x8 bn;
            if (ks < 15) bn = *(const bf16x8*)(bAp + (ks + 1) * 32);   // prefetch next
            #pragma unroll
            for (int mt = 0; mt < 6; ++mt) {
                bf16x8 af = *(const bf16x8*)(Xh + xswc(mt * 16 + lr, ks * 32 + lg * 8));
                acc[mt] = __builtin_amdgcn_mfma_f32_16x16x32_bf16(af, bc, acc[mt], 0, 0, 0);
            }
            if (ks < 15) bc = bn;
        }
        {
            float bias = bsel[h * 64 + colh];
            #pragma unroll
            for (int mt = 0; mt < 6; ++mt)
                #pragma unroll
                for (int j = 0; j < 4; ++j)
                    T[qsw(mt * 16 + lg * 4 + j, colh)] = f2bf(acc[mt][j] + bias);
        }
        __syncthreads();   // Q/K/V complete

        // ---------------- attention (waves 0-7 <-> batch items 0-7) ----------------
        if (w < 8) {
            f32x4 sacc = (f32x4){0.f, 0.f, 0.f, 0.f};
            #pragma unroll
            for (int k2 = 0; k2 < 2; ++k2) {
                bf16x8 ak = *(const bf16x8*)(Kh + qsw(rb + lr12, k2 * 32 + lg * 8));
                bf16x8 aq = *(const bf16x8*)(Qh + qsw(rb + lr12, k2 * 32 + lg * 8));
                sacc = __builtin_amdgcn_mfma_f32_16x16x32_bf16(ak, aq, sacc, 0, 0, 0);
            }
            float ab4[4] = {0.f, 0.f, 0.f, 0.f};
            if (lg < 3 && lr < 12) {
                float4 t4 = *(const float4*)(adj + (h * S_LEN + lr) * S_LEN + lg * 4);
                ab4[0] = t4.x; ab4[1] = t4.y; ab4[2] = t4.z; ab4[3] = t4.w;
            }
            float sc[4], e4[4];
            float m = -1e30f;
            #pragma unroll
            for (int j = 0; j < 4; ++j) {
                int t = lg * 4 + j;
                sc[j] = (t < 12) ? (sacc[j] * 0.125f + ab4[j]) : -1e30f;
                m = fmaxf(m, sc[j]);
            }
            m = fmaxf(m, __shfl_xor(m, 16));
            m = fmaxf(m, __shfl_xor(m, 32));
            float ssum = 0.f;
            #pragma unroll
            for (int j = 0; j < 4; ++j) { e4[j] = __expf(sc[j] - m); ssum += e4[j]; }
            ssum += __shfl_xor(ssum, 16);
            ssum += __shfl_xor(ssum, 32);
            float inv = 1.f / ssum;
            float* Pw = Pl + w * 240;
            if (lr < 12 && lg < 3) {
                f32x4 pvec = (f32x4){e4[0] * inv, e4[1] * inv, e4[2] * inv, e4[3] * inv};
                *(f32x4*)(Pw + lr * 20 + lg * 4) = pvec;
            }
            // same-wave P write -> read: no barrier needed (validated R5-R21)
            float vv[12];
            #pragma unroll
            for (int t = 0; t < 12; ++t) vv[t] = bf2f(Vh[qsw(rb + t, lane)]);
            #pragma unroll
            for (int ss = 0; ss < 12; ++ss) {
                f32x4 pa = *(const f32x4*)(Pw + ss * 20);
                f32x4 pb = *(const f32x4*)(Pw + ss * 20 + 4);
                f32x4 pc = *(const f32x4*)(Pw + ss * 20 + 8);
                float o = 0.f;
                #pragma unroll
                for (int t = 0; t < 4; ++t) o += pa[t] * vv[t];
                #pragma unroll
                for (int t = 0; t < 4; ++t) o += pb[t] * vv[4 + t];
                #pragma unroll
                for (int t = 0; t < 4; ++t) o += pc[t] * vv[8 + t];
                // bf16 A, packed: row r's data at u16-elem r*1024 + col
                aout[(row0 + rb + ss) * 1024 + h * 64 + lane] = f2bf(o);
            }
        }
        __syncthreads();   // A consumers done; safe to overwrite Q/K/V next head
    }
}

// ---------------- kernel 2: out-proj + bias + residual + LayerNorm (in-place) ----------------
__global__ __launch_bounds__(THREADS2, 2) void oproj_ln(
    const float* __restrict__ x, const unsigned short* __restrict__ wt,
    const float* __restrict__ bo, const float* __restrict__ gamma,
    const float* __restrict__ beta, float* __restrict__ out)
{
    extern __shared__ char smem[];
    unsigned short* Ast = (unsigned short*)(smem + AST_OFF);  // [96][512] bf16
    float* red   = (float*)(smem + RED_OFF);   // [96][17]
    float* musig = (float*)(smem + MU_OFF);    // [96][2]

    const int tid  = threadIdx.x;
    const int lane = tid & 63;
    const int w    = tid >> 6;          // wave 0..7, cols [w*64, w*64+64)
    const int lr   = lane & 15;
    const int lg   = lane >> 4;
    const size_t row0 = (size_t)blockIdx.x * ROWS2;
    const unsigned short* abase = (const unsigned short*)out;  // bf16 A region

    // stage A (bf16, low half of each row's f32 slot) -> LDS, straight 16B copy.
    // 6144 chunks of 8 u16, 12/thread. In-place safe: reads precede the barrier,
    // and this block's f32 writes cover exactly these rows.
    #pragma unroll
    for (int it = 0; it < 12; ++it) {
        int idx = it * THREADS2 + tid;
        int r = idx >> 6, c8 = (idx & 63) << 3;
        uint4 v = *(const uint4*)(abase + (row0 + r) * 1024 + c8);
        *(uint4*)(Ast + xswc(r, c8)) = v;
    }
    __syncthreads();

    f32x4 Y[6][4];
    #pragma unroll
    for (int mt = 0; mt < 6; ++mt)
        #pragma unroll
        for (int nt = 0; nt < 4; ++nt) Y[mt][nt] = (f32x4){0.f, 0.f, 0.f, 0.f};

    const unsigned short* obase = wt + (size_t)3 * WMAT + (w * 64 + lr) * D_DIM;
    #pragma unroll 1
    for (int ks = 0; ks < 16; ++ks) {
        bf16x8 afr[6];
        #pragma unroll
        for (int mt = 0; mt < 6; ++mt)
            afr[mt] = *(const bf16x8*)(Ast + xswc(mt * 16 + lr, ks * 32 + lg * 8));
        #pragma unroll
        for (int nt = 0; nt < 4; ++nt) {
            bf16x8 bfr = *(const bf16x8*)(obase + nt * 16 * D_DIM + ks * 32 + lg * 8);
            #pragma unroll
            for (int mt = 0; mt < 6; ++mt)
                Y[mt][nt] = __builtin_amdgcn_mfma_f32_16x16x32_bf16(afr[mt], bfr, Y[mt][nt], 0, 0, 0);
        }
    }

    // epilogue: +bo, +x (fp32), LayerNorm, store
    float bo4[4], gm4[4], bt4[4];
    int cols[4];
    #pragma unroll
    for (int nt = 0; nt < 4; ++nt) {
        cols[nt] = w * 64 + nt * 16 + lr;
        bo4[nt] = bo[cols[nt]]; gm4[nt] = gamma[cols[nt]]; bt4[nt] = beta[cols[nt]];
    }
    #pragma unroll
    for (int mt = 0; mt < 6; ++mt)
        #pragma unroll
        for (int j = 0; j < 4; ++j) {
            int rowl = mt * 16 + lg * 4 + j;
            const float* xrow = x + (row0 + rowl) * (size_t)D_DIM;
            float ps = 0.f, pq = 0.f;
            #pragma unroll
            for (int nt = 0; nt < 4; ++nt) {
                float y = Y[mt][nt][j] + bo4[nt] + xrow[cols[nt]];
                Y[mt][nt][j] = y;
                ps += y; pq += y * y;
            }
            ps += __shfl_xor(ps, 1); pq += __shfl_xor(pq, 1);
            ps += __shfl_xor(ps, 2); pq += __shfl_xor(pq, 2);
            ps += __shfl_xor(ps, 4); pq += __shfl_xor(pq, 4);
            ps += __shfl_xor(ps, 8); pq += __shfl_xor(pq, 8);
            if (lr == 0) { red[rowl * 17 + w * 2] = ps; red[rowl * 17 + w * 2 + 1] = pq; }
        }
    __syncthreads();
    if (tid < ROWS2) {
        float s = 0.f, q = 0.f;
        #pragma unroll
        for (int w8 = 0; w8 < 8; ++w8) { s += red[tid * 17 + w8 * 2]; q += red[tid * 17 + w8 * 2 + 1]; }
        float mu = s * (1.f / 512.f);
        float var = q * (1.f / 512.f) - mu * mu;
        musig[tid * 2] = mu;
        musig[tid * 2 + 1] = rsqrtf(var + 1e-5f);
    }
    __syncthreads();
    #pragma unroll
    for (int mt = 0; mt < 6; ++mt)
        #pragma unroll
        for (int j = 0; j < 4; ++j) {
            int rowl = mt * 16 + lg * 4 + j;
            float mu = musig[rowl * 2], rs = musig[rowl * 2 + 1];
            float* orow = out + (row0 + rowl) * (size_t)D_DIM;
            #pragma unroll
            for (int nt = 0; nt < 4; ++nt)
                orow[cols[nt]] = (Y[mt][nt][j] - mu) * rs * gm4[nt] + bt4[nt];
        }
}

extern "C" void kernel_launch(void* const* d_in, const int* in_sizes, int n_in,
                              void* d_out, int out_size, void* d_ws, size_t ws_size,
                              hipStream_t stream) {
    (void)in_sizes; (void)n_in; (void)out_size; (void)ws_size;
    const float* x     = (const float*)d_in[0];
    const float* Wq    = (const float*)d_in[1];
    const float* bq    = (const float*)d_in[2];
    const float* Wk    = (const float*)d_in[3];
    const float* bk    = (const float*)d_in[4];
    const float* Wv    = (const float*)d_in[5];
    const float* bv    = (const float*)d_in[6];
    const float* adj   = (const float*)d_in[7];
    const float* Wo    = (const float*)d_in[8];
    const float* bo    = (const float*)d_in[9];
    const float* gamma = (const float*)d_in[10];
    const float* beta  = (const float*)d_in[11];
    unsigned short* wt = (unsigned short*)d_ws;      // 4 * 512*512 bf16 = 2 MiB

    prep_weights<<<4096, 256, 0, stream>>>(Wq, Wk, Wv, Wo, wt);
    qkv_attn<<<16384 / G_B1, THREADS1, SMEM1, stream>>>(
        x, wt, bq, bk, bv, adj, (unsigned short*)d_out);
    oproj_ln<<<16384 / G_B2, THREADS2, SMEM2, stream>>>(
        x, wt, bo, gamma, beta, (float*)d_out);
}